// Round 1
// baseline (438.620 us; speedup 1.0000x reference)
//
#include <hip/hip_runtime.h>
#include <hip/hip_bf16.h>
#include <cstdint>
#include <cstddef>

#define S_LEN 2048
#define D_HEAD 64
#define NBH 32                      // B*H = 2*16
#define NELEM 4194304               // NBH * S_LEN * D_HEAD

typedef __attribute__((ext_vector_type(8))) short short8;
typedef __attribute__((ext_vector_type(4))) float f32x4;

__device__ __forceinline__ short f2bf(float f) {
    union { float f; uint32_t u; } v; v.f = f;
    uint32_t u = v.u + 0x7FFFu + ((v.u >> 16) & 1u);   // RNE, inputs finite
    return (short)(u >> 16);
}

// K fp32 -> bf16, same layout
__global__ void convert_k_kernel(const float* __restrict__ K, short* __restrict__ Kb) {
    int i = blockIdx.x * 256 + threadIdx.x;            // grid sized exactly
    float4 x = reinterpret_cast<const float4*>(K)[i];
    short4 y;
    y.x = f2bf(x.x); y.y = f2bf(x.y); y.z = f2bf(x.z); y.w = f2bf(x.w);
    reinterpret_cast<short4*>(Kb)[i] = y;
}

// V fp32 [bh][S][D] -> bf16 transposed [bh][D][S]
__global__ void transpose_v_kernel(const float* __restrict__ V, short* __restrict__ Vtb) {
    __shared__ float tile[64][65];
    const int bh = blockIdx.y;
    const int s0 = blockIdx.x * 64;
    const int d = threadIdx.x & 63;
    const int r = threadIdx.x >> 6;
    const float* vp = V + ((size_t)bh * S_LEN + s0) * D_HEAD;
    #pragma unroll
    for (int i = 0; i < 16; ++i) {
        int s = i * 4 + r;
        tile[s][d] = vp[(size_t)s * D_HEAD + d];
    }
    __syncthreads();
    short* op = Vtb + (size_t)bh * (D_HEAD * S_LEN) + s0;
    #pragma unroll
    for (int i = 0; i < 16; ++i) {
        int dd = i * 4 + r;
        op[(size_t)dd * S_LEN + d] = f2bf(tile[d][dd]);
    }
}

// One wave = 16 query rows, full flash pass over S. 4 independent waves/block.
__launch_bounds__(256, 2)
__global__ void attn_kernel(const float* __restrict__ Q,
                            const short* __restrict__ Kb,
                            const short* __restrict__ Vtb,
                            float* __restrict__ Out,
                            float* __restrict__ P) {
    __shared__ __align__(16) short T[4][16][40];       // wave-private transpose tiles

    const int lane = threadIdx.x & 63;
    const int w    = threadIdx.x >> 6;
    const int bh   = blockIdx.y;
    const int qbase = blockIdx.x * 64 + w * 16;
    const int lrow = lane & 15;
    const int lgrp = lane >> 4;
    const float scale = 0.125f;                        // 1/sqrt(64)

    // Q A-fragments: row = lrow, k = lgrp*8 + e (+32 for second k-step)
    short8 a0, a1;
    {
        const float* qr = Q + ((size_t)bh * S_LEN + qbase + lrow) * D_HEAD + lgrp * 8;
        #pragma unroll
        for (int e = 0; e < 8; ++e) a0[e] = f2bf(qr[e]);
        #pragma unroll
        for (int e = 0; e < 8; ++e) a1[e] = f2bf(qr[e + 32]);
    }

    const short* Kp = Kb + (size_t)bh * (S_LEN * D_HEAD);
    const short* Vp = Vtb + (size_t)bh * (D_HEAD * S_LEN);

    // ---- pass 1: softmax denominators (no max subtraction: |score| <= ~6) ----
    float lacc[4] = {0.f, 0.f, 0.f, 0.f};
    for (int j0 = 0; j0 < S_LEN; j0 += 32) {
        #pragma unroll
        for (int ct = 0; ct < 2; ++ct) {
            const short* kr = Kp + (size_t)(j0 + ct * 16 + lrow) * D_HEAD + lgrp * 8;
            short8 b0 = *reinterpret_cast<const short8*>(kr);
            short8 b1 = *reinterpret_cast<const short8*>(kr + 32);
            f32x4 c = {0.f, 0.f, 0.f, 0.f};
            c = __builtin_amdgcn_mfma_f32_16x16x32_bf16(a0, b0, c, 0, 0, 0);
            c = __builtin_amdgcn_mfma_f32_16x16x32_bf16(a1, b1, c, 0, 0, 0);
            #pragma unroll
            for (int rr = 0; rr < 4; ++rr) lacc[rr] += __expf(c[rr] * scale);
        }
    }
    #pragma unroll
    for (int rr = 0; rr < 4; ++rr) {
        lacc[rr] += __shfl_xor(lacc[rr], 1);
        lacc[rr] += __shfl_xor(lacc[rr], 2);
        lacc[rr] += __shfl_xor(lacc[rr], 4);
        lacc[rr] += __shfl_xor(lacc[rr], 8);
    }
    float rl[4];
    #pragma unroll
    for (int rr = 0; rr < 4; ++rr) rl[rr] = 1.0f / lacc[rr];

    // ---- pass 2: write p = e/l, accumulate PV (unnormalized e in bf16) ----
    f32x4 acc[4] = {};
    float* plb = P + (size_t)bh * S_LEN * S_LEN + (size_t)(qbase + lgrp * 4) * S_LEN + lrow;

    for (int j0 = 0; j0 < S_LEN; j0 += 32) {
        #pragma unroll
        for (int ct = 0; ct < 2; ++ct) {
            const short* kr = Kp + (size_t)(j0 + ct * 16 + lrow) * D_HEAD + lgrp * 8;
            short8 b0 = *reinterpret_cast<const short8*>(kr);
            short8 b1 = *reinterpret_cast<const short8*>(kr + 32);
            f32x4 c = {0.f, 0.f, 0.f, 0.f};
            c = __builtin_amdgcn_mfma_f32_16x16x32_bf16(a0, b0, c, 0, 0, 0);
            c = __builtin_amdgcn_mfma_f32_16x16x32_bf16(a1, b1, c, 0, 0, 0);
            #pragma unroll
            for (int rr = 0; rr < 4; ++rr) {
                float e = __expf(c[rr] * scale);
                plb[(size_t)rr * S_LEN + j0 + ct * 16] = e * rl[rr];
                T[w][lgrp * 4 + rr][ct * 16 + lrow] = f2bf(e);
            }
        }
        // order wave-private LDS write -> read (no block barrier: keeps vmcnt open)
        asm volatile("s_waitcnt lgkmcnt(0)" ::: "memory");
        short8 pa = *reinterpret_cast<const short8*>(&T[w][lrow][lgrp * 8]);
        asm volatile("s_waitcnt lgkmcnt(0)" ::: "memory");
        #pragma unroll
        for (int vt = 0; vt < 4; ++vt) {
            const short* vr = Vp + (size_t)(vt * 16 + lrow) * S_LEN + j0 + lgrp * 8;
            short8 bv = *reinterpret_cast<const short8*>(vr);
            acc[vt] = __builtin_amdgcn_mfma_f32_16x16x32_bf16(pa, bv, acc[vt], 0, 0, 0);
        }
    }

    float* ob = Out + ((size_t)bh * S_LEN + qbase + lgrp * 4) * D_HEAD + lrow;
    #pragma unroll
    for (int vt = 0; vt < 4; ++vt) {
        #pragma unroll
        for (int rr = 0; rr < 4; ++rr) {
            ob[(size_t)rr * D_HEAD + vt * 16] = acc[vt][rr] * rl[rr];
        }
    }
}

extern "C" void kernel_launch(void* const* d_in, const int* in_sizes, int n_in,
                              void* d_out, int out_size, void* d_ws, size_t ws_size,
                              hipStream_t stream) {
    const float* Q = (const float*)d_in[0];
    const float* K = (const float*)d_in[1];
    const float* V = (const float*)d_in[2];
    float* Out = (float*)d_out;
    float* P = Out + (size_t)NELEM;                    // outputs concatenated flat
    short* Kb = (short*)d_ws;                          // 8.4 MB
    short* Vtb = Kb + (size_t)NELEM;                   // 8.4 MB (needs ws >= 16.8 MB)

    convert_k_kernel<<<NELEM / (256 * 4), 256, 0, stream>>>(K, Kb);
    transpose_v_kernel<<<dim3(S_LEN / 64, NBH), 256, 0, stream>>>(V, Vtb);
    attn_kernel<<<dim3(S_LEN / 64, NBH), 256, 0, stream>>>(Q, Kb, Vtb, Out, P);
}

// Round 2
// 371.547 us; speedup vs baseline: 1.1805x; 1.1805x over previous
//
#include <hip/hip_runtime.h>
#include <hip/hip_bf16.h>
#include <cstdint>
#include <cstddef>

#define S_LEN 2048
#define D_HEAD 64
#define NBH 32                      // B*H = 2*16
#define NELEM 4194304               // NBH * S_LEN * D_HEAD
#define SUP 128                     // columns per store superblock

typedef __attribute__((ext_vector_type(8))) short short8;
typedef __attribute__((ext_vector_type(4))) float f32x4;

__device__ __forceinline__ short f2bf(float f) {
    union { float f; uint32_t u; } v; v.f = f;
    uint32_t u = v.u + 0x7FFFu + ((v.u >> 16) & 1u);   // RNE, inputs finite
    return (short)(u >> 16);
}

__device__ __forceinline__ uint32_t pkbf(float lo, float hi) {
    return ((uint32_t)(uint16_t)f2bf(hi) << 16) | (uint32_t)(uint16_t)f2bf(lo);
}

// K fp32 -> bf16, same layout
__global__ void convert_k_kernel(const float* __restrict__ K, short* __restrict__ Kb) {
    int i = blockIdx.x * 256 + threadIdx.x;
    float4 x = reinterpret_cast<const float4*>(K)[i];
    short4 y;
    y.x = f2bf(x.x); y.y = f2bf(x.y); y.z = f2bf(x.z); y.w = f2bf(x.w);
    reinterpret_cast<short4*>(Kb)[i] = y;
}

// V fp32 [bh][S][D] -> bf16 transposed [bh][D][S]
__global__ void transpose_v_kernel(const float* __restrict__ V, short* __restrict__ Vtb) {
    __shared__ float tile[64][65];
    const int bh = blockIdx.y;
    const int s0 = blockIdx.x * 64;
    const int d = threadIdx.x & 63;
    const int r = threadIdx.x >> 6;
    const float* vp = V + ((size_t)bh * S_LEN + s0) * D_HEAD;
    #pragma unroll
    for (int i = 0; i < 16; ++i) {
        int s = i * 4 + r;
        tile[s][d] = vp[(size_t)s * D_HEAD + d];
    }
    __syncthreads();
    short* op = Vtb + (size_t)bh * (D_HEAD * S_LEN) + s0;
    #pragma unroll
    for (int i = 0; i < 16; ++i) {
        int dd = i * 4 + r;
        op[(size_t)dd * S_LEN + d] = f2bf(tile[d][dd]);
    }
}

// One wave = 16 query rows. Swapped QK^T: mfma(A=K, B=Q) -> lane holds p for
// q = lane&15 at k = (lane>>4)*4 + reg (+16 per ct tile). p is staged in a
// swizzled LDS buffer per 128 columns, then burst-written (512B/row bursts).
__launch_bounds__(256, 2)
__global__ void attn_kernel(const float* __restrict__ Q,
                            const short* __restrict__ Kb,
                            const short* __restrict__ Vtb,
                            float* __restrict__ Out,
                            float* __restrict__ P) {
    __shared__ __align__(16) float stage[4][16][SUP];  // 32 KB: p f32 staging
    __shared__ __align__(16) short pvt[4][16][40];     // 5 KB: bf16 PV A-frag tile

    const int lane = threadIdx.x & 63;
    const int w    = threadIdx.x >> 6;
    const int bh   = blockIdx.y;
    const int qbase = blockIdx.x * 64 + w * 16;
    const int lrow = lane & 15;
    const int lgrp = lane >> 4;
    const float scale = 0.125f;                        // 1/sqrt(64)

    // Q fragment (B operand: col = lane&15 = q-row, d = lgrp*8+e)
    short8 q0, q1;
    {
        const float* qr = Q + ((size_t)bh * S_LEN + qbase + lrow) * D_HEAD + lgrp * 8;
        #pragma unroll
        for (int e = 0; e < 8; ++e) q0[e] = f2bf(qr[e]);
        #pragma unroll
        for (int e = 0; e < 8; ++e) q1[e] = f2bf(qr[e + 32]);
    }

    const short* Kp = Kb + (size_t)bh * (S_LEN * D_HEAD);
    const short* Vp = Vtb + (size_t)bh * (D_HEAD * S_LEN);

    // ---- pass 1: softmax denominator (scalar per lane: q = lrow) ----
    float l = 0.f;
    for (int j0 = 0; j0 < S_LEN; j0 += 32) {
        const short* kr0 = Kp + (size_t)(j0 + lrow) * D_HEAD + lgrp * 8;
        const short* kr1 = kr0 + 16 * D_HEAD;
        short8 k00 = *reinterpret_cast<const short8*>(kr0);
        short8 k01 = *reinterpret_cast<const short8*>(kr0 + 32);
        short8 k10 = *reinterpret_cast<const short8*>(kr1);
        short8 k11 = *reinterpret_cast<const short8*>(kr1 + 32);
        f32x4 c0 = {0.f, 0.f, 0.f, 0.f};
        f32x4 c1 = {0.f, 0.f, 0.f, 0.f};
        c0 = __builtin_amdgcn_mfma_f32_16x16x32_bf16(k00, q0, c0, 0, 0, 0);
        c0 = __builtin_amdgcn_mfma_f32_16x16x32_bf16(k01, q1, c0, 0, 0, 0);
        c1 = __builtin_amdgcn_mfma_f32_16x16x32_bf16(k10, q0, c1, 0, 0, 0);
        c1 = __builtin_amdgcn_mfma_f32_16x16x32_bf16(k11, q1, c1, 0, 0, 0);
        #pragma unroll
        for (int rr = 0; rr < 4; ++rr)
            l += __expf(c0[rr] * scale) + __expf(c1[rr] * scale);
    }
    l += __shfl_xor(l, 16);
    l += __shfl_xor(l, 32);
    const float rl = 1.0f / l;

    // ---- pass 2: recompute scores, stage normalized p, burst-store, PV ----
    f32x4 acc[4] = {};
    char* stg = (char*)&stage[w][0][0];
    char* pvw = (char*)&pvt[w][0][0];
    const int swz = (lrow & 7) << 4;
    float* Pb = P + (size_t)bh * S_LEN * S_LEN;

    for (int sup = 0; sup < S_LEN; sup += SUP) {
        #pragma unroll
        for (int jj = 0; jj < SUP / 32; ++jj) {
            const int j0 = sup + jj * 32;
            const short* kr0 = Kp + (size_t)(j0 + lrow) * D_HEAD + lgrp * 8;
            const short* kr1 = kr0 + 16 * D_HEAD;
            short8 k00 = *reinterpret_cast<const short8*>(kr0);
            short8 k01 = *reinterpret_cast<const short8*>(kr0 + 32);
            short8 k10 = *reinterpret_cast<const short8*>(kr1);
            short8 k11 = *reinterpret_cast<const short8*>(kr1 + 32);
            short8 bv0 = *reinterpret_cast<const short8*>(Vp + (size_t)(0 * 16 + lrow) * S_LEN + j0 + lgrp * 8);
            short8 bv1 = *reinterpret_cast<const short8*>(Vp + (size_t)(1 * 16 + lrow) * S_LEN + j0 + lgrp * 8);
            short8 bv2 = *reinterpret_cast<const short8*>(Vp + (size_t)(2 * 16 + lrow) * S_LEN + j0 + lgrp * 8);
            short8 bv3 = *reinterpret_cast<const short8*>(Vp + (size_t)(3 * 16 + lrow) * S_LEN + j0 + lgrp * 8);
            f32x4 c0 = {0.f, 0.f, 0.f, 0.f};
            f32x4 c1 = {0.f, 0.f, 0.f, 0.f};
            c0 = __builtin_amdgcn_mfma_f32_16x16x32_bf16(k00, q0, c0, 0, 0, 0);
            c0 = __builtin_amdgcn_mfma_f32_16x16x32_bf16(k01, q1, c0, 0, 0, 0);
            c1 = __builtin_amdgcn_mfma_f32_16x16x32_bf16(k10, q0, c1, 0, 0, 0);
            c1 = __builtin_amdgcn_mfma_f32_16x16x32_bf16(k11, q1, c1, 0, 0, 0);

            f32x4 p0, p1;
            #pragma unroll
            for (int rr = 0; rr < 4; ++rr) {
                p0[rr] = __expf(c0[rr] * scale) * rl;
                p1[rr] = __expf(c1[rr] * scale) * rl;
            }

            // stage normalized p (f32, swizzled): col = jj*32 + ct*16 + lgrp*4
            *(f32x4*)(stg + ((lrow * 512 + ((jj * 32 + lgrp * 4) << 2)) ^ swz)) = p0;
            *(f32x4*)(stg + ((lrow * 512 + ((jj * 32 + 16 + lgrp * 4) << 2)) ^ swz)) = p1;

            // PV A-frag tile (bf16): row q=lrow, cols ct*16 + lgrp*4 + rr
            *(uint2*)(pvw + lrow * 80 + lgrp * 8)      = make_uint2(pkbf(p0[0], p0[1]), pkbf(p0[2], p0[3]));
            *(uint2*)(pvw + lrow * 80 + 32 + lgrp * 8) = make_uint2(pkbf(p1[0], p1[1]), pkbf(p1[2], p1[3]));

            asm volatile("s_waitcnt lgkmcnt(0)" ::: "memory");
            short8 pa = *reinterpret_cast<const short8*>(pvw + lrow * 80 + lgrp * 16);
            acc[0] = __builtin_amdgcn_mfma_f32_16x16x32_bf16(pa, bv0, acc[0], 0, 0, 0);
            acc[1] = __builtin_amdgcn_mfma_f32_16x16x32_bf16(pa, bv1, acc[1], 0, 0, 0);
            acc[2] = __builtin_amdgcn_mfma_f32_16x16x32_bf16(pa, bv2, acc[2], 0, 0, 0);
            acc[3] = __builtin_amdgcn_mfma_f32_16x16x32_bf16(pa, bv3, acc[3], 0, 0, 0);
        }

        asm volatile("s_waitcnt lgkmcnt(0)" ::: "memory");
        // burst store: 2 rows x 512B contiguous per instruction, nontemporal
        #pragma unroll
        for (int rb = 0; rb < 8; ++rb) {
            const int r = rb * 2 + (lane >> 5);
            const int c = lane & 31;
            f32x4 pv = *(const f32x4*)(stg + ((r * 512 + c * 16) ^ ((r & 7) << 4)));
            __builtin_nontemporal_store(pv,
                (f32x4*)(Pb + (size_t)(qbase + r) * S_LEN + sup + c * 4));
        }
    }

    // epilogue: Out[q = lgrp*4+rr][d = vt*16+lrow], already normalized
    float* ob = Out + ((size_t)bh * S_LEN + qbase + lgrp * 4) * D_HEAD + lrow;
    #pragma unroll
    for (int vt = 0; vt < 4; ++vt) {
        #pragma unroll
        for (int rr = 0; rr < 4; ++rr) {
            ob[(size_t)rr * D_HEAD + vt * 16] = acc[vt][rr];
        }
    }
}

extern "C" void kernel_launch(void* const* d_in, const int* in_sizes, int n_in,
                              void* d_out, int out_size, void* d_ws, size_t ws_size,
                              hipStream_t stream) {
    const float* Q = (const float*)d_in[0];
    const float* K = (const float*)d_in[1];
    const float* V = (const float*)d_in[2];
    float* Out = (float*)d_out;
    float* P = Out + (size_t)NELEM;                    // outputs concatenated flat
    short* Kb = (short*)d_ws;                          // 8.4 MB
    short* Vtb = Kb + (size_t)NELEM;                   // 8.4 MB (needs ws >= 16.8 MB)

    convert_k_kernel<<<NELEM / (256 * 4), 256, 0, stream>>>(K, Kb);
    transpose_v_kernel<<<dim3(S_LEN / 64, NBH), 256, 0, stream>>>(V, Vtb);
    attn_kernel<<<dim3(S_LEN / 64, NBH), 256, 0, stream>>>(Q, Kb, Vtb, Out, P);
}